// Round 7
// baseline (2461.456 us; speedup 1.0000x reference)
//
#include <hip/hip_runtime.h>

#define C 128
#define THREADS 256      // all kernels: 256 threads = 4 waves
#define TILE 64          // node rows per block (fp32 kernels)
#define EPW 16           // edges per MFMA tile (one wave-tile)
#define GTILES 8         // tiles per wave (software pipeline depth amortizer)
#define LDSPAD 8
#define LDSW (C + LDSPAD)    // 136 ushorts/row -> conflict-free row stride

typedef unsigned short ushortT;
typedef __attribute__((ext_vector_type(8))) short short8;
typedef __attribute__((ext_vector_type(8))) ushortT ushort8;
typedef __attribute__((ext_vector_type(4))) float floatx4;

// ---- bf16 helpers (RNE) ----
__device__ __forceinline__ ushortT f2bf(float x) {
    union { float f; unsigned u; } v; v.f = x;
    unsigned r = v.u + 0x7FFFu + ((v.u >> 16) & 1u);
    return (ushortT)(r >> 16);
}
__device__ __forceinline__ float bf2f(ushortT h) {
    union { unsigned u; float f; } v; v.u = ((unsigned)h) << 16;
    return v.f;
}
__device__ __forceinline__ void atomic_add_f32(float* p, float v) {
    __hip_atomic_fetch_add(p, v, __ATOMIC_RELAXED, __HIP_MEMORY_SCOPE_AGENT);
}

// ============================================================================
// fp32 micro-GEMM helpers for node-level kernels
// ============================================================================
__device__ __forceinline__ void zero_acc(float acc[8][4]) {
#pragma unroll
    for (int j = 0; j < 8; ++j)
#pragma unroll
        for (int i = 0; i < 4; ++i) acc[j][i] = 0.f;
}

__device__ __forceinline__ void tile_gemm(const float* __restrict__ s_in,
                                          const float* __restrict__ W,
                                          float acc[8][4], int rg, int oc0)
{
#pragma unroll 2
    for (int kc = 0; kc < C; kc += 4) {
        const float4 w0 = *(const float4*)(W + (kc + 0) * C + oc0);
        const float4 w1 = *(const float4*)(W + (kc + 1) * C + oc0);
        const float4 w2 = *(const float4*)(W + (kc + 2) * C + oc0);
        const float4 w3 = *(const float4*)(W + (kc + 3) * C + oc0);
#pragma unroll
        for (int j = 0; j < 8; ++j) {
            const float4 a = *(const float4*)(s_in + (rg * 8 + j) * C + kc);
            acc[j][0] = fmaf(a.w, w3.x, fmaf(a.z, w2.x, fmaf(a.y, w1.x, fmaf(a.x, w0.x, acc[j][0]))));
            acc[j][1] = fmaf(a.w, w3.y, fmaf(a.z, w2.y, fmaf(a.y, w1.y, fmaf(a.x, w0.y, acc[j][1]))));
            acc[j][2] = fmaf(a.w, w3.z, fmaf(a.z, w2.z, fmaf(a.y, w1.z, fmaf(a.x, w0.z, acc[j][2]))));
            acc[j][3] = fmaf(a.w, w3.w, fmaf(a.z, w2.w, fmaf(a.y, w1.w, fmaf(a.x, w0.w, acc[j][3]))));
        }
    }
}

__device__ __forceinline__ void bias_relu(float acc[8][4], const float* __restrict__ b, int oc0) {
    const float4 bv = *(const float4*)(b + oc0);
#pragma unroll
    for (int j = 0; j < 8; ++j) {
        acc[j][0] = fmaxf(acc[j][0] + bv.x, 0.f);
        acc[j][1] = fmaxf(acc[j][1] + bv.y, 0.f);
        acc[j][2] = fmaxf(acc[j][2] + bv.z, 0.f);
        acc[j][3] = fmaxf(acc[j][3] + bv.w, 0.f);
    }
}

__device__ __forceinline__ void store_tile(float* __restrict__ s, const float acc[8][4], int rg, int oc0) {
#pragma unroll
    for (int j = 0; j < 8; ++j) {
        float4 t; t.x = acc[j][0]; t.y = acc[j][1]; t.z = acc[j][2]; t.w = acc[j][3];
        *(float4*)(s + (rg * 8 + j) * C + oc0) = t;
    }
}

// ============================================================================
// pack 4 weight matrices into MFMA B-fragment order (bf16), f = ks*8+nt
// lane L holds k = ks*32 + (L>>4)*8 + j,  n = nt*16 + (L&15)
// ============================================================================
extern "C" __global__ void pack_w(const float* __restrict__ w0, const float* __restrict__ w1,
                                  const float* __restrict__ w2, const float* __restrict__ w3,
                                  ushortT* __restrict__ out)
{
    const int t = blockIdx.x * 256 + threadIdx.x;      // 65536 threads
    const int j = t & 7, lane = (t >> 3) & 63, f = (t >> 9) & 31, s = t >> 14;
    const float* W = (s == 0) ? w0 : (s == 1) ? w1 : (s == 2) ? w2 : w3;
    const int nt = f & 7, ks = f >> 3;
    const int n = nt * 16 + (lane & 15);
    const int k = ks * 32 + (lane >> 4) * 8 + j;
    out[t] = f2bf(W[k * C + n]);
}

extern "C" __global__ void cvt_bf(const float* __restrict__ in, ushortT* __restrict__ out, int n)
{
    const int t = blockIdx.x * 256 + threadIdx.x;
    if (t < n) out[t] = f2bf(in[t]);
}

// ============================================================================
// kernel 1: h = relu(x@W_in+b_in); q_bf; k_bf; v_bf (all bf16 tables)
// ============================================================================
extern "C" __global__ void __launch_bounds__(THREADS)
node_qkv(const float* __restrict__ x,
         const float* __restrict__ W_in, const float* __restrict__ b_in,
         const float* __restrict__ W_lin, const float* __restrict__ W_src, const float* __restrict__ W_dst,
         ushortT* __restrict__ q_bf, ushortT* __restrict__ k_bf, ushortT* __restrict__ v_bf, int N)
{
    __shared__ __align__(16) float s_in[TILE * C];
    const int tx = threadIdx.x;
    const int rg = tx >> 5;
    const int oc0 = (tx & 31) << 2;
    const int row0 = blockIdx.x * TILE;

#pragma unroll
    for (int j = 0; j < 8; ++j) {
        const int r = rg * 8 + j, n = row0 + r;
        float4 xv; xv.x = xv.y = xv.z = xv.w = 0.f;
        if (n < N) xv = *(const float4*)(x + n * C + oc0);
        *(float4*)(s_in + r * C + oc0) = xv;
    }

    float acc[8][4];
    zero_acc(acc);
    tile_gemm(s_in, W_in, acc, rg, oc0);
    bias_relu(acc, b_in, oc0);
    store_tile(s_in, acc, rg, oc0);          // s_in = h

    ushortT* outs[3];
    const float* Ws[3];
    outs[0] = q_bf; outs[1] = k_bf; outs[2] = v_bf;
    Ws[0] = W_dst;  Ws[1] = W_src;  Ws[2] = W_lin;
#pragma unroll
    for (int m = 0; m < 3; ++m) {
        zero_acc(acc);
        tile_gemm(s_in, Ws[m], acc, rg, oc0);
#pragma unroll
        for (int j = 0; j < 8; ++j) {
            const int n = row0 + rg * 8 + j;
            if (n < N) {
                ushort4 t; t.x = f2bf(acc[j][0]); t.y = f2bf(acc[j][1]);
                t.z = f2bf(acc[j][2]); t.w = f2bf(acc[j][3]);
                *(ushort4*)(outs[m] + (size_t)n * C + oc0) = t;
            }
        }
    }
}

// ============================================================================
// kernel 2 (MFMA, software-pipelined): each wave runs GTILES consecutive
// 16-edge tiles; next tile's 5 row-gathers are issued mid-chain so their
// latency hides under the current tile's 128 MFMAs + epilogue.
// Per-wave private LDS slabs (A + V), NO barriers.
// A-frag:  A[m=lane&15][k=quad*8+j]     C-frag: C[m=quad*4+r][n=lane&15]
// ============================================================================
__device__ __forceinline__ void gather4(const ushortT* __restrict__ base, int node, int seg,
                                        ushort8 dst[4])
{
    const ushort8* p = (const ushort8*)(base + (size_t)node * C + seg * 32);
    dst[0] = p[0]; dst[1] = p[1]; dst[2] = p[2]; dst[3] = p[3];
}

__device__ __forceinline__ void wave_gemm1(const ushortT (*A)[LDSW],
                                           const ushortT* __restrict__ Bp,
                                           int quad, int m16, int lane,
                                           floatx4 acc[8])
{
#pragma unroll
    for (int ks = 0; ks < 4; ++ks) {
        const short8 af = *(const short8*)&A[m16][ks * 32 + quad * 8];
#pragma unroll
        for (int nt = 0; nt < 8; ++nt) {
            const short8 bf = *(const short8*)(Bp + ((size_t)((ks * 8 + nt) * 64 + lane)) * 8);
            acc[nt] = __builtin_amdgcn_mfma_f32_16x16x32_bf16(af, bf, acc[nt], 0, 0, 0);
        }
    }
}

__device__ __forceinline__ void zero8(floatx4 acc[8]) {
#pragma unroll
    for (int nt = 0; nt < 8; ++nt) { acc[nt][0]=0.f; acc[nt][1]=0.f; acc[nt][2]=0.f; acc[nt][3]=0.f; }
}

__device__ __forceinline__ void cstore_relu(ushortT (*A)[LDSW], floatx4 acc[8],
                                            const float* __restrict__ bias, int quad, int m16)
{
#pragma unroll
    for (int nt = 0; nt < 8; ++nt) {
        const float b = bias[nt * 16 + m16];
#pragma unroll
        for (int r = 0; r < 4; ++r)
            A[quad * 4 + r][nt * 16 + m16] = f2bf(fmaxf(acc[nt][r] + b, 0.f));
    }
}

extern "C" __global__ void __launch_bounds__(THREADS, 2)   // 2 waves/SIMD = empirical residency; full VGPR budget
edge_mfma(const ushortT* __restrict__ pos_bf, const int* __restrict__ ei,
          const ushortT* __restrict__ q_bf, const ushortT* __restrict__ k_bf,
          const ushortT* __restrict__ v_bf, const ushortT* __restrict__ Bpack,
          const float* __restrict__ pb1, const float* __restrict__ pb2,
          const float* __restrict__ ab1, const float* __restrict__ ab2,
          float* __restrict__ z, float* __restrict__ aggU, int E)
{
    __shared__ ushortT Aslab[4][EPW][LDSW];   // 17.4 KB
    __shared__ ushortT Vslab[4][EPW][LDSW];   // 17.4 KB
    const int tid = threadIdx.x;
    const int wv = tid >> 6, lane = tid & 63;
    const int quad = lane >> 4, m16 = lane & 15;
    const int row = lane >> 2, seg = lane & 3;     // staging mapping
    ushortT (*A)[LDSW] = Aslab[wv];
    ushortT (*V)[LDSW] = Vslab[wv];

    const int wave_base = (blockIdx.x * 4 + wv) * (GTILES * EPW);

    // ---- prologue: tile-0 indices + gathers ----
    int ssr[4], sdr[4];
    ushort8 Pd[4], Ps[4], Qv[4], Kv[4], Vv[4];
    {
        const int eidx = min(wave_base + row, E - 1);
        const int esS = ei[eidx], edS = ei[E + eidx];
#pragma unroll
        for (int r = 0; r < 4; ++r) {
            const int e = min(wave_base + quad * 4 + r, E - 1);
            ssr[r] = ei[e]; sdr[r] = ei[E + e];
        }
        gather4(pos_bf, edS, seg, Pd); gather4(pos_bf, esS, seg, Ps);
        gather4(q_bf,  edS, seg, Qv); gather4(k_bf,  esS, seg, Kv);
        gather4(v_bf,  esS, seg, Vv);
    }

    for (int t = 0; t < GTILES; ++t) {
        const int e_base = wave_base + t * EPW;

        // ---- next-tile indices (clamped; last iter's prefetch is wasted-but-safe) ----
        int n_esS, n_edS, n_ssr[4], n_sdr[4];
        {
            const int nb = e_base + EPW;
            const int eidx = min(nb + row, E - 1);
            n_esS = ei[eidx]; n_edS = ei[E + eidx];
#pragma unroll
            for (int r = 0; r < 4; ++r) {
                const int e = min(nb + quad * 4 + r, E - 1);
                n_ssr[r] = ei[e]; n_sdr[r] = ei[E + e];
            }
        }

        // ---- A0 = bf16(pos[dst] - pos[src]) ----
#pragma unroll
        for (int i = 0; i < 4; ++i) {
            ushort8 o;
#pragma unroll
            for (int u = 0; u < 8; ++u) o[u] = f2bf(bf2f(Pd[i][u]) - bf2f(Ps[i][u]));
            *(ushort8*)&A[row][seg * 32 + i * 8] = o;
        }
        // prefetch next pos rows (consumed at next iteration's A0)
        gather4(pos_bf, n_edS, seg, Pd); gather4(pos_bf, n_esS, seg, Ps);

        floatx4 acc[8];

        // ---- pos_nn layer 1 ----
        zero8(acc);
        wave_gemm1(A, Bpack + 0 * 16384, quad, m16, lane, acc);
        cstore_relu(A, acc, pb1, quad, m16);

        // ---- pos_nn layer 2 -> delta (packed regs + slab) ----
        zero8(acc);
        wave_gemm1(A, Bpack + 1 * 16384, quad, m16, lane, acc);
        unsigned dlp[8][2];
#pragma unroll
        for (int nt = 0; nt < 8; ++nt) {
            const float b = pb2[nt * 16 + m16];
            ushortT d[4];
#pragma unroll
            for (int r = 0; r < 4; ++r) {
                d[r] = f2bf(fmaxf(acc[nt][r] + b, 0.f));
                A[quad * 4 + r][nt * 16 + m16] = d[r];
            }
            dlp[nt][0] = (unsigned)d[0] | ((unsigned)d[1] << 16);
            dlp[nt][1] = (unsigned)d[2] | ((unsigned)d[3] << 16);
        }

        // ---- stage v rows into Vslab (read back in C-layout at epilogue) ----
#pragma unroll
        for (int i = 0; i < 4; ++i)
            *(ushort8*)&V[row][seg * 32 + i * 8] = Vv[i];

        // ---- A2 = bf16( q[dst] - k[src] + delta ) ----
#pragma unroll
        for (int i = 0; i < 4; ++i) {
            ushort8 dv = *(ushort8*)&A[row][seg * 32 + i * 8], o;
#pragma unroll
            for (int u = 0; u < 8; ++u)
                o[u] = f2bf(bf2f(Qv[i][u]) - bf2f(Kv[i][u]) + bf2f(dv[u]));
            *(ushort8*)&A[row][seg * 32 + i * 8] = o;
        }
        // prefetch next q/k/v rows
        gather4(q_bf, n_edS, seg, Qv); gather4(k_bf, n_esS, seg, Kv);
        gather4(v_bf, n_esS, seg, Vv);

        // ---- attn_nn layer 1 ----
        zero8(acc);
        wave_gemm1(A, Bpack + 2 * 16384, quad, m16, lane, acc);
        cstore_relu(A, acc, ab1, quad, m16);

        // ---- attn_nn layer 2 -> ea = exp(relu(alpha+b)) ----
        zero8(acc);
        wave_gemm1(A, Bpack + 3 * 16384, quad, m16, lane, acc);
#pragma unroll
        for (int nt = 0; nt < 8; ++nt) {
            const float b = ab2[nt * 16 + m16];
#pragma unroll
            for (int r = 0; r < 4; ++r)
                acc[nt][r] = __expf(fmaxf(acc[nt][r] + b, 0.f));  // alpha>=0, O(1): no max-shift
        }

        // ---- zero ea for out-of-range edges ----
        if (e_base + EPW > E) {
#pragma unroll
            for (int r = 0; r < 4; ++r)
                if (e_base + quad * 4 + r >= E) {
#pragma unroll
                    for (int nt = 0; nt < 8; ++nt) acc[nt][r] = 0.f;
                }
        }

        // ---- epilogue: z += ea; aggU += ea*(v+delta); v from Vslab ----
#pragma unroll
        for (int nt = 0; nt < 8; ++nt) {
            const int c = nt * 16 + m16;
#pragma unroll
            for (int r = 0; r < 4; ++r) {
                const float ea  = acc[nt][r];
                const float dlv = bf2f((ushortT)(dlp[nt][r >> 1] >> (16 * (r & 1))));
                const float vv  = bf2f(V[quad * 4 + r][c]);
                atomic_add_f32(z    + (size_t)sdr[r] * C + c, ea);
                atomic_add_f32(aggU + (size_t)sdr[r] * C + c, ea * (vv + dlv));
            }
        }

        // ---- rotate epilogue indices ----
#pragma unroll
        for (int r = 0; r < 4; ++r) { ssr[r] = n_ssr[r]; sdr[r] = n_sdr[r]; }
    }
}

// ============================================================================
// kernel 3: out = relu( (aggU / (z+1e-16)) @ W_out + b_out )
// ============================================================================
extern "C" __global__ void __launch_bounds__(THREADS)
out_kernel(const float* __restrict__ aggU, const float* __restrict__ z,
           const float* __restrict__ W_out, const float* __restrict__ b_out,
           float* __restrict__ out, int N)
{
    __shared__ __align__(16) float s_in[TILE * C];
    const int tx = threadIdx.x;
    const int rg = tx >> 5;
    const int oc0 = (tx & 31) << 2;
    const int row0 = blockIdx.x * TILE;

#pragma unroll
    for (int j = 0; j < 8; ++j) {
        const int r = rg * 8 + j, n = row0 + r;
        float4 a; a.x = a.y = a.z = a.w = 0.f;
        if (n < N) {
            const float4 g  = *(const float4*)(aggU + (size_t)n * C + oc0);
            const float4 zz = *(const float4*)(z    + (size_t)n * C + oc0);
            a.x = g.x / (zz.x + 1e-16f);
            a.y = g.y / (zz.y + 1e-16f);
            a.z = g.z / (zz.z + 1e-16f);
            a.w = g.w / (zz.w + 1e-16f);
        }
        *(float4*)(s_in + r * C + oc0) = a;
    }

    float acc[8][4];
    zero_acc(acc);
    tile_gemm(s_in, W_out, acc, rg, oc0);
    bias_relu(acc, b_out, oc0);
#pragma unroll
    for (int j = 0; j < 8; ++j) {
        const int n = row0 + rg * 8 + j;
        if (n < N) { float4 t; t.x=acc[j][0]; t.y=acc[j][1]; t.z=acc[j][2]; t.w=acc[j][3];
                     *(float4*)(out + (size_t)n * C + oc0) = t; }
    }
}

// ---------------------------------------------------------------------------
extern "C" void kernel_launch(void* const* d_in, const int* in_sizes, int n_in,
                              void* d_out, int out_size, void* d_ws, size_t ws_size,
                              hipStream_t stream)
{
    const float* x     = (const float*)d_in[0];
    const float* pos   = (const float*)d_in[1];
    const int*   ei    = (const int*)  d_in[2];
    const float* W_in  = (const float*)d_in[3];
    const float* b_in  = (const float*)d_in[4];
    const float* W_lin = (const float*)d_in[5];
    const float* W_src = (const float*)d_in[6];
    const float* W_dst = (const float*)d_in[7];
    const float* pw1   = (const float*)d_in[8];
    const float* pb1   = (const float*)d_in[9];
    const float* pw2   = (const float*)d_in[10];
    const float* pb2   = (const float*)d_in[11];
    const float* aw1   = (const float*)d_in[12];
    const float* ab1   = (const float*)d_in[13];
    const float* aw2   = (const float*)d_in[14];
    const float* ab2   = (const float*)d_in[15];
    const float* W_out = (const float*)d_in[16];
    const float* b_out = (const float*)d_in[17];

    const int N = in_sizes[0] / C;
    const int E = in_sizes[2] / 2;
    const size_t NC = (size_t)N * C;

    float*   z      = (float*)d_ws;                          // [N,C] fp32
    float*   aggU   = z    + NC;                             // [N,C] fp32
    ushortT* q_bf   = (ushortT*)(aggU + NC);                 // [N,C] bf16
    ushortT* k_bf   = q_bf + NC;                             // [N,C] bf16
    ushortT* v_bf   = k_bf + NC;                             // [N,C] bf16
    ushortT* pos_bf = v_bf + NC;                             // [N,C] bf16
    ushortT* Bpack  = pos_bf + NC;                           // 65536 bf16 = 128 KB

    hipMemsetAsync(z, 0, 2 * NC * sizeof(float), stream);

    pack_w<<<256, 256, 0, stream>>>(pw1, pw2, aw1, aw2, Bpack);
    cvt_bf<<<((int)NC + 255) / 256, 256, 0, stream>>>(pos, pos_bf, (int)NC);

    const int nb = (N + TILE - 1) / TILE;
    const int edges_per_block = 4 * GTILES * EPW;            // 512
    const int eb = (E + edges_per_block - 1) / edges_per_block;

    node_qkv<<<nb, THREADS, 0, stream>>>(x, W_in, b_in, W_lin, W_src, W_dst, q_bf, k_bf, v_bf, N);
    edge_mfma<<<eb, THREADS, 0, stream>>>(pos_bf, ei, q_bf, k_bf, v_bf, Bpack,
                                          pb1, pb2, ab1, ab2, z, aggU, E);
    out_kernel<<<nb, THREADS, 0, stream>>>(aggU, z, W_out, b_out, (float*)d_out, N);
}

// Round 8
// 1007.703 us; speedup vs baseline: 2.4426x; 2.4426x over previous
//
#include <hip/hip_runtime.h>
#include <hip/hip_bf16.h>

#define C 128
#define THREADS 256      // 4 waves/block
#define TILE 64          // node rows per block (fp32 kernels)
#define EPW 16           // edges per wave-tile
#define GTILES 8         // tiles per wave, steady-state loop (NOT unrolled)
#define LDSPAD 8
#define LDSW (C + LDSPAD)    // 136 ushorts/row

typedef unsigned short ushortT;
typedef __attribute__((ext_vector_type(8))) short short8;
typedef __attribute__((ext_vector_type(8))) ushortT ushort8;
typedef __attribute__((ext_vector_type(4))) float floatx4;
typedef __attribute__((ext_vector_type(4))) unsigned uintx4;

// ---- bf16 helpers ----
__device__ __forceinline__ ushortT f2bf(float x) {
    union { float f; unsigned u; } v; v.f = x;
    unsigned r = v.u + 0x7FFFu + ((v.u >> 16) & 1u);
    return (ushortT)(r >> 16);
}
__device__ __forceinline__ float bf2f(ushortT h) {
    union { unsigned u; float f; } v; v.u = ((unsigned)h) << 16;
    return v.f;
}
__device__ __forceinline__ float2 upk2(unsigned u) {            // 2x bf16 -> float2
    union { unsigned u; __hip_bfloat162 h; } cv; cv.u = u;
    return __bfloat1622float2(cv.h);
}
__device__ __forceinline__ unsigned pk2(float a, float b) {     // float2 -> 2x bf16 (RNE)
    float2 f; f.x = a; f.y = b;
    union { unsigned u; __hip_bfloat162 h; } cv; cv.h = __float22bfloat162_rn(f);
    return cv.u;
}
__device__ __forceinline__ void atomic_add_f32(float* p, float v) {
    __hip_atomic_fetch_add(p, v, __ATOMIC_RELAXED, __HIP_MEMORY_SCOPE_AGENT);
}

// ============================================================================
// fp32 micro-GEMM helpers for node-level kernels
// ============================================================================
__device__ __forceinline__ void zero_acc(float acc[8][4]) {
#pragma unroll
    for (int j = 0; j < 8; ++j)
#pragma unroll
        for (int i = 0; i < 4; ++i) acc[j][i] = 0.f;
}

__device__ __forceinline__ void tile_gemm(const float* __restrict__ s_in,
                                          const float* __restrict__ W,
                                          float acc[8][4], int rg, int oc0)
{
#pragma unroll 2
    for (int kc = 0; kc < C; kc += 4) {
        const float4 w0 = *(const float4*)(W + (kc + 0) * C + oc0);
        const float4 w1 = *(const float4*)(W + (kc + 1) * C + oc0);
        const float4 w2 = *(const float4*)(W + (kc + 2) * C + oc0);
        const float4 w3 = *(const float4*)(W + (kc + 3) * C + oc0);
#pragma unroll
        for (int j = 0; j < 8; ++j) {
            const float4 a = *(const float4*)(s_in + (rg * 8 + j) * C + kc);
            acc[j][0] = fmaf(a.w, w3.x, fmaf(a.z, w2.x, fmaf(a.y, w1.x, fmaf(a.x, w0.x, acc[j][0]))));
            acc[j][1] = fmaf(a.w, w3.y, fmaf(a.z, w2.y, fmaf(a.y, w1.y, fmaf(a.x, w0.y, acc[j][1]))));
            acc[j][2] = fmaf(a.w, w3.z, fmaf(a.z, w2.z, fmaf(a.y, w1.z, fmaf(a.x, w0.z, acc[j][2]))));
            acc[j][3] = fmaf(a.w, w3.w, fmaf(a.z, w2.w, fmaf(a.y, w1.w, fmaf(a.x, w0.w, acc[j][3]))));
        }
    }
}

__device__ __forceinline__ void bias_relu(float acc[8][4], const float* __restrict__ b, int oc0) {
    const float4 bv = *(const float4*)(b + oc0);
#pragma unroll
    for (int j = 0; j < 8; ++j) {
        acc[j][0] = fmaxf(acc[j][0] + bv.x, 0.f);
        acc[j][1] = fmaxf(acc[j][1] + bv.y, 0.f);
        acc[j][2] = fmaxf(acc[j][2] + bv.z, 0.f);
        acc[j][3] = fmaxf(acc[j][3] + bv.w, 0.f);
    }
}

__device__ __forceinline__ void store_tile(float* __restrict__ s, const float acc[8][4], int rg, int oc0) {
#pragma unroll
    for (int j = 0; j < 8; ++j) {
        float4 t; t.x = acc[j][0]; t.y = acc[j][1]; t.z = acc[j][2]; t.w = acc[j][3];
        *(float4*)(s + (rg * 8 + j) * C + oc0) = t;
    }
}

// ============================================================================
// pack 4 weight matrices into MFMA B-fragment order (bf16), f = ks*8+nt
// lane L holds k = ks*32 + (L>>4)*8 + j,  n = nt*16 + (L&15)
// ============================================================================
extern "C" __global__ void pack_w(const float* __restrict__ w0, const float* __restrict__ w1,
                                  const float* __restrict__ w2, const float* __restrict__ w3,
                                  ushortT* __restrict__ out)
{
    const int t = blockIdx.x * 256 + threadIdx.x;      // 65536 threads
    const int j = t & 7, lane = (t >> 3) & 63, f = (t >> 9) & 31, s = t >> 14;
    const float* W = (s == 0) ? w0 : (s == 1) ? w1 : (s == 2) ? w2 : w3;
    const int nt = f & 7, ks = f >> 3;
    const int n = nt * 16 + (lane & 15);
    const int k = ks * 32 + (lane >> 4) * 8 + j;
    out[t] = f2bf(W[k * C + n]);
}

extern "C" __global__ void cvt_bf(const float* __restrict__ in, ushortT* __restrict__ out, int n)
{
    const int t = blockIdx.x * 256 + threadIdx.x;
    if (t < n) out[t] = f2bf(in[t]);
}

// ============================================================================
// kernel 1: h = relu(x@W_in+b_in); q_bf; k_bf; v_bf
// ============================================================================
extern "C" __global__ void __launch_bounds__(THREADS)
node_qkv(const float* __restrict__ x,
         const float* __restrict__ W_in, const float* __restrict__ b_in,
         const float* __restrict__ W_lin, const float* __restrict__ W_src, const float* __restrict__ W_dst,
         ushortT* __restrict__ q_bf, ushortT* __restrict__ k_bf, ushortT* __restrict__ v_bf, int N)
{
    __shared__ __align__(16) float s_in[TILE * C];
    const int tx = threadIdx.x;
    const int rg = tx >> 5;
    const int oc0 = (tx & 31) << 2;
    const int row0 = blockIdx.x * TILE;

#pragma unroll
    for (int j = 0; j < 8; ++j) {
        const int r = rg * 8 + j, n = row0 + r;
        float4 xv; xv.x = xv.y = xv.z = xv.w = 0.f;
        if (n < N) xv = *(const float4*)(x + n * C + oc0);
        *(float4*)(s_in + r * C + oc0) = xv;
    }

    float acc[8][4];
    zero_acc(acc);
    tile_gemm(s_in, W_in, acc, rg, oc0);
    bias_relu(acc, b_in, oc0);
    store_tile(s_in, acc, rg, oc0);          // s_in = h

    ushortT* outs[3];
    const float* Ws[3];
    outs[0] = q_bf; outs[1] = k_bf; outs[2] = v_bf;
    Ws[0] = W_dst;  Ws[1] = W_src;  Ws[2] = W_lin;
#pragma unroll 1
    for (int m = 0; m < 3; ++m) {
        zero_acc(acc);
        tile_gemm(s_in, Ws[m], acc, rg, oc0);
#pragma unroll
        for (int j = 0; j < 8; ++j) {
            const int n = row0 + rg * 8 + j;
            if (n < N) {
                ushort4 t; t.x = f2bf(acc[j][0]); t.y = f2bf(acc[j][1]);
                t.z = f2bf(acc[j][2]); t.w = f2bf(acc[j][3]);
                *(ushort4*)(outs[m] + (size_t)n * C + oc0) = t;
            }
        }
    }
}

// ============================================================================
// kernel 2 (MFMA): COMPACT-CODE version. 16 edges/wave-tile, GTILES-deep
// steady-state loop (not unrolled) so the body stays resident in L1I.
// Per-wave private LDS slabs, NO barriers, no reg-prefetch (R7 spill lesson).
// A-frag:  A[m=lane&15][k=quad*8+j]     C-frag: C[m=quad*4+r][n=lane&15]
// ============================================================================
__device__ __forceinline__ void gather4(const ushortT* __restrict__ base, int node, int seg,
                                        ushort8 dst[4])
{
    const ushort8* p = (const ushort8*)(base + (size_t)node * C + seg * 32);
    dst[0] = p[0]; dst[1] = p[1]; dst[2] = p[2]; dst[3] = p[3];
}

__device__ __forceinline__ void wave_gemm(const ushortT (*A)[LDSW],
                                          const ushortT* __restrict__ Bp,
                                          int quad, int m16, int lane,
                                          floatx4 acc[8])
{
#pragma unroll
    for (int nt = 0; nt < 8; ++nt) { acc[nt][0]=0.f; acc[nt][1]=0.f; acc[nt][2]=0.f; acc[nt][3]=0.f; }
#pragma unroll 1
    for (int ks = 0; ks < 4; ++ks) {
        const short8 af = *(const short8*)&A[m16][ks * 32 + quad * 8];
        const ushortT* bpk = Bp + (size_t)ks * 4096 + (size_t)lane * 8;
#pragma unroll
        for (int nt = 0; nt < 8; ++nt) {
            const short8 bf = *(const short8*)(bpk + nt * 512);
            acc[nt] = __builtin_amdgcn_mfma_f32_16x16x32_bf16(af, bf, acc[nt], 0, 0, 0);
        }
    }
}

__device__ __forceinline__ void cstore_relu_r(ushortT (*A)[LDSW], floatx4 acc[8],
                                              const float bias[8], int quad, int m16)
{
#pragma unroll
    for (int nt = 0; nt < 8; ++nt) {
        const float b = bias[nt];
#pragma unroll
        for (int r = 0; r < 4; r += 2) {
            const unsigned p = pk2(fmaxf(acc[nt][r] + b, 0.f), fmaxf(acc[nt][r + 1] + b, 0.f));
            A[quad * 4 + r][nt * 16 + m16]     = (ushortT)(p & 0xffffu);
            A[quad * 4 + r + 1][nt * 16 + m16] = (ushortT)(p >> 16);
        }
    }
}

extern "C" __global__ void __launch_bounds__(THREADS)
edge_mfma(const ushortT* __restrict__ pos_bf, const int* __restrict__ ei,
          const ushortT* __restrict__ q_bf, const ushortT* __restrict__ k_bf,
          const ushortT* __restrict__ v_bf, const ushortT* __restrict__ Bpack,
          const float* __restrict__ pb1, const float* __restrict__ pb2,
          const float* __restrict__ ab1, const float* __restrict__ ab2,
          float* __restrict__ z, float* __restrict__ aggU, int E)
{
    __shared__ ushortT Aslab[4][EPW][LDSW];   // 17.4 KB
    __shared__ ushortT Vslab[4][EPW][LDSW];   // 17.4 KB
    const int tid = threadIdx.x;
    const int wv = tid >> 6, lane = tid & 63;
    const int quad = lane >> 4, m16 = lane & 15;
    const int row = lane >> 2, seg = lane & 3;
    ushortT (*A)[LDSW] = Aslab[wv];
    ushortT (*V)[LDSW] = Vslab[wv];

    // tile-invariant: biases in registers (removes per-tile VMEM + keeps body small)
    float pb1v[8], pb2v[8], ab1v[8], ab2v[8];
#pragma unroll
    for (int nt = 0; nt < 8; ++nt) {
        pb1v[nt] = pb1[nt * 16 + m16]; pb2v[nt] = pb2[nt * 16 + m16];
        ab1v[nt] = ab1[nt * 16 + m16]; ab2v[nt] = ab2[nt * 16 + m16];
    }

    const ushortT* B0 = Bpack;
    const ushortT* B1 = Bpack + 16384;
    const ushortT* B2 = Bpack + 32768;
    const ushortT* B3 = Bpack + 49152;

    const int wave_base = (blockIdx.x * 4 + wv) * (GTILES * EPW);

#pragma unroll 1
    for (int t = 0; t < GTILES; ++t) {
        const int e_base = wave_base + t * EPW;
        const int eidx = min(e_base + row, E - 1);
        const int es = ei[eidx], ed = ei[E + eidx];
        int sdr[4];
#pragma unroll
        for (int r = 0; r < 4; ++r)
            sdr[r] = ei[E + min(e_base + quad * 4 + r, E - 1)];

        ushort8 Pd[4], Ps[4], Qv[4], Kv[4], Vv[4];
        gather4(pos_bf, ed, seg, Pd); gather4(pos_bf, es, seg, Ps);
        gather4(q_bf,  ed, seg, Qv); gather4(k_bf,  es, seg, Kv);
        gather4(v_bf,  es, seg, Vv);

        // ---- A0 = bf16(pos[dst] - pos[src]); stage v into Vslab ----
#pragma unroll
        for (int i = 0; i < 4; ++i) {
            const uintx4 pd = *(const uintx4*)&Pd[i];
            const uintx4 ps = *(const uintx4*)&Ps[i];
            uintx4 o;
#pragma unroll
            for (int w = 0; w < 4; ++w) {
                const float2 a = upk2(pd[w]), b = upk2(ps[w]);
                o[w] = pk2(a.x - b.x, a.y - b.y);
            }
            *(uintx4*)&A[row][seg * 32 + i * 8] = o;
            *(ushort8*)&V[row][seg * 32 + i * 8] = Vv[i];
        }

        floatx4 acc[8];

        // ---- pos_nn layer 1 ----
        wave_gemm(A, B0, quad, m16, lane, acc);
        cstore_relu_r(A, acc, pb1v, quad, m16);

        // ---- pos_nn layer 2 -> delta (packed regs + slab) ----
        wave_gemm(A, B1, quad, m16, lane, acc);
        unsigned dlp[8][2];
#pragma unroll
        for (int nt = 0; nt < 8; ++nt) {
            const float b = pb2v[nt];
            const unsigned p0 = pk2(fmaxf(acc[nt][0] + b, 0.f), fmaxf(acc[nt][1] + b, 0.f));
            const unsigned p1 = pk2(fmaxf(acc[nt][2] + b, 0.f), fmaxf(acc[nt][3] + b, 0.f));
            dlp[nt][0] = p0; dlp[nt][1] = p1;
            A[quad * 4 + 0][nt * 16 + m16] = (ushortT)(p0 & 0xffffu);
            A[quad * 4 + 1][nt * 16 + m16] = (ushortT)(p0 >> 16);
            A[quad * 4 + 2][nt * 16 + m16] = (ushortT)(p1 & 0xffffu);
            A[quad * 4 + 3][nt * 16 + m16] = (ushortT)(p1 >> 16);
        }

        // ---- A2 = bf16( q[dst] - k[src] + delta ) ----
#pragma unroll
        for (int i = 0; i < 4; ++i) {
            const uintx4 dv = *(const uintx4*)&A[row][seg * 32 + i * 8];
            const uintx4 qv = *(const uintx4*)&Qv[i];
            const uintx4 kv = *(const uintx4*)&Kv[i];
            uintx4 o;
#pragma unroll
            for (int w = 0; w < 4; ++w) {
                const float2 qq = upk2(qv[w]), kk = upk2(kv[w]), dd = upk2(dv[w]);
                o[w] = pk2(qq.x - kk.x + dd.x, qq.y - kk.y + dd.y);
            }
            *(uintx4*)&A[row][seg * 32 + i * 8] = o;
        }

        // ---- attn_nn layer 1 ----
        wave_gemm(A, B2, quad, m16, lane, acc);
        cstore_relu_r(A, acc, ab1v, quad, m16);

        // ---- attn_nn layer 2 -> ea = exp(relu(alpha+b)) ----
        wave_gemm(A, B3, quad, m16, lane, acc);
#pragma unroll
        for (int nt = 0; nt < 8; ++nt) {
            const float b = ab2v[nt];
#pragma unroll
            for (int r = 0; r < 4; ++r)
                acc[nt][r] = __expf(fmaxf(acc[nt][r] + b, 0.f));  // alpha>=0, O(1): no max-shift
        }

        // ---- zero ea for out-of-range edges ----
        if (e_base + EPW > E) {
#pragma unroll
            for (int r = 0; r < 4; ++r)
                if (e_base + quad * 4 + r >= E) {
#pragma unroll
                    for (int nt = 0; nt < 8; ++nt) acc[nt][r] = 0.f;
                }
        }

        // ---- epilogue: z += ea; aggU += ea*(v+delta) ----
#pragma unroll
        for (int r = 0; r < 4; ++r) {
            float* zp = z    + (size_t)sdr[r] * C + m16;
            float* gp = aggU + (size_t)sdr[r] * C + m16;
#pragma unroll
            for (int nt = 0; nt < 8; ++nt) {
                const float ea  = acc[nt][r];
                const float2 dpair = upk2(dlp[nt][r >> 1]);
                const float dlv = (r & 1) ? dpair.y : dpair.x;
                const float vv  = bf2f(V[quad * 4 + r][nt * 16 + m16]);
                atomic_add_f32(zp + nt * 16, ea);
                atomic_add_f32(gp + nt * 16, ea * (vv + dlv));
            }
        }
    }
}

// ============================================================================
// kernel 3: out = relu( (aggU / (z+1e-16)) @ W_out + b_out )
// ============================================================================
extern "C" __global__ void __launch_bounds__(THREADS)
out_kernel(const float* __restrict__ aggU, const float* __restrict__ z,
           const float* __restrict__ W_out, const float* __restrict__ b_out,
           float* __restrict__ out, int N)
{
    __shared__ __align__(16) float s_in[TILE * C];
    const int tx = threadIdx.x;
    const int rg = tx >> 5;
    const int oc0 = (tx & 31) << 2;
    const int row0 = blockIdx.x * TILE;

#pragma unroll
    for (int j = 0; j < 8; ++j) {
        const int r = rg * 8 + j, n = row0 + r;
        float4 a; a.x = a.y = a.z = a.w = 0.f;
        if (n < N) {
            const float4 g  = *(const float4*)(aggU + (size_t)n * C + oc0);
            const float4 zz = *(const float4*)(z    + (size_t)n * C + oc0);
            a.x = g.x / (zz.x + 1e-16f);
            a.y = g.y / (zz.y + 1e-16f);
            a.z = g.z / (zz.z + 1e-16f);
            a.w = g.w / (zz.w + 1e-16f);
        }
        *(float4*)(s_in + r * C + oc0) = a;
    }

    float acc[8][4];
    zero_acc(acc);
    tile_gemm(s_in, W_out, acc, rg, oc0);
    bias_relu(acc, b_out, oc0);
#pragma unroll
    for (int j = 0; j < 8; ++j) {
        const int n = row0 + rg * 8 + j;
        if (n < N) { float4 t; t.x=acc[j][0]; t.y=acc[j][1]; t.z=acc[j][2]; t.w=acc[j][3];
                     *(float4*)(out + (size_t)n * C + oc0) = t; }
    }
}

// ---------------------------------------------------------------------------
extern "C" void kernel_launch(void* const* d_in, const int* in_sizes, int n_in,
                              void* d_out, int out_size, void* d_ws, size_t ws_size,
                              hipStream_t stream)
{
    const float* x     = (const float*)d_in[0];
    const float* pos   = (const float*)d_in[1];
    const int*   ei    = (const int*)  d_in[2];
    const float* W_in  = (const float*)d_in[3];
    const float* b_in  = (const float*)d_in[4];
    const float* W_lin = (const float*)d_in[5];
    const float* W_src = (const float*)d_in[6];
    const float* W_dst = (const float*)d_in[7];
    const float* pw1   = (const float*)d_in[8];
    const float* pb1   = (const float*)d_in[9];
    const float* pw2   = (const float*)d_in[10];
    const float* pb2   = (const float*)d_in[11];
    const float* aw1   = (const float*)d_in[12];
    const float* ab1   = (const float*)d_in[13];
    const float* aw2   = (const float*)d_in[14];
    const float* ab2   = (const float*)d_in[15];
    const float* W_out = (const float*)d_in[16];
    const float* b_out = (const float*)d_in[17];

    const int N = in_sizes[0] / C;
    const int E = in_sizes[2] / 2;
    const size_t NC = (size_t)N * C;

    float*   z      = (float*)d_ws;                          // [N,C] fp32
    float*   aggU   = z    + NC;                             // [N,C] fp32
    ushortT* q_bf   = (ushortT*)(aggU + NC);                 // [N,C] bf16
    ushortT* k_bf   = q_bf + NC;                             // [N,C] bf16
    ushortT* v_bf   = k_bf + NC;                             // [N,C] bf16
    ushortT* pos_bf = v_bf + NC;                             // [N,C] bf16
    ushortT* Bpack  = pos_bf + NC;                           // 65536 bf16 = 128 KB

    hipMemsetAsync(z, 0, 2 * NC * sizeof(float), stream);

    pack_w<<<256, 256, 0, stream>>>(pw1, pw2, aw1, aw2, Bpack);
    cvt_bf<<<((int)NC + 255) / 256, 256, 0, stream>>>(pos, pos_bf, (int)NC);

    const int nb = (N + TILE - 1) / TILE;
    const int edges_per_block = 4 * GTILES * EPW;            // 512
    const int eb = (E + edges_per_block - 1) / edges_per_block;

    node_qkv<<<nb, THREADS, 0, stream>>>(x, W_in, b_in, W_lin, W_src, W_dst, q_bf, k_bf, v_bf, N);
    edge_mfma<<<eb, THREADS, 0, stream>>>(pos_bf, ei, q_bf, k_bf, v_bf, Bpack,
                                          pb1, pb2, ab1, ab2, z, aggU, E);
    out_kernel<<<nb, THREADS, 0, stream>>>(aggU, z, W_out, b_out, (float*)d_out, N);
}

// Round 9
// 1005.260 us; speedup vs baseline: 2.4486x; 1.0024x over previous
//
#include <hip/hip_runtime.h>
#include <hip/hip_bf16.h>

#define C 128
#define THREADS 256      // 4 waves/block
#define TILE 64          // node rows per block (fp32 kernels)
#define EPW 16           // edges per wave-tile
#define GTILES 8         // tiles per wave, steady-state loop (NOT unrolled)
#define LDSPAD 8
#define LDSW (C + LDSPAD)    // 136 ushorts/row

typedef unsigned short ushortT;
typedef __attribute__((ext_vector_type(8))) short short8;
typedef __attribute__((ext_vector_type(8))) ushortT ushort8;
typedef __attribute__((ext_vector_type(4))) float floatx4;
typedef __attribute__((ext_vector_type(4))) unsigned uintx4;

// ---- bf16 helpers ----
__device__ __forceinline__ ushortT f2bf(float x) {
    union { float f; unsigned u; } v; v.f = x;
    unsigned r = v.u + 0x7FFFu + ((v.u >> 16) & 1u);
    return (ushortT)(r >> 16);
}
__device__ __forceinline__ float bf2f(ushortT h) {
    union { unsigned u; float f; } v; v.u = ((unsigned)h) << 16;
    return v.f;
}
__device__ __forceinline__ float2 upk2(unsigned u) {            // 2x bf16 -> float2
    union { unsigned u; __hip_bfloat162 h; } cv; cv.u = u;
    return __bfloat1622float2(cv.h);
}
__device__ __forceinline__ unsigned pk2(float a, float b) {     // float2 -> 2x bf16 (RNE)
    float2 f; f.x = a; f.y = b;
    union { unsigned u; __hip_bfloat162 h; } cv; cv.h = __float22bfloat162_rn(f);
    return cv.u;
}
__device__ __forceinline__ void atomic_add_f32(float* p, float v) {
    __hip_atomic_fetch_add(p, v, __ATOMIC_RELAXED, __HIP_MEMORY_SCOPE_AGENT);
}

// ============================================================================
// fp32 micro-GEMM helpers for node-level kernels
// ============================================================================
__device__ __forceinline__ void zero_acc(float acc[8][4]) {
#pragma unroll
    for (int j = 0; j < 8; ++j)
#pragma unroll
        for (int i = 0; i < 4; ++i) acc[j][i] = 0.f;
}

__device__ __forceinline__ void tile_gemm(const float* __restrict__ s_in,
                                          const float* __restrict__ W,
                                          float acc[8][4], int rg, int oc0)
{
#pragma unroll 2
    for (int kc = 0; kc < C; kc += 4) {
        const float4 w0 = *(const float4*)(W + (kc + 0) * C + oc0);
        const float4 w1 = *(const float4*)(W + (kc + 1) * C + oc0);
        const float4 w2 = *(const float4*)(W + (kc + 2) * C + oc0);
        const float4 w3 = *(const float4*)(W + (kc + 3) * C + oc0);
#pragma unroll
        for (int j = 0; j < 8; ++j) {
            const float4 a = *(const float4*)(s_in + (rg * 8 + j) * C + kc);
            acc[j][0] = fmaf(a.w, w3.x, fmaf(a.z, w2.x, fmaf(a.y, w1.x, fmaf(a.x, w0.x, acc[j][0]))));
            acc[j][1] = fmaf(a.w, w3.y, fmaf(a.z, w2.y, fmaf(a.y, w1.y, fmaf(a.x, w0.y, acc[j][1]))));
            acc[j][2] = fmaf(a.w, w3.z, fmaf(a.z, w2.z, fmaf(a.y, w1.z, fmaf(a.x, w0.z, acc[j][2]))));
            acc[j][3] = fmaf(a.w, w3.w, fmaf(a.z, w2.w, fmaf(a.y, w1.w, fmaf(a.x, w0.w, acc[j][3]))));
        }
    }
}

__device__ __forceinline__ void bias_relu(float acc[8][4], const float* __restrict__ b, int oc0) {
    const float4 bv = *(const float4*)(b + oc0);
#pragma unroll
    for (int j = 0; j < 8; ++j) {
        acc[j][0] = fmaxf(acc[j][0] + bv.x, 0.f);
        acc[j][1] = fmaxf(acc[j][1] + bv.y, 0.f);
        acc[j][2] = fmaxf(acc[j][2] + bv.z, 0.f);
        acc[j][3] = fmaxf(acc[j][3] + bv.w, 0.f);
    }
}

__device__ __forceinline__ void store_tile(float* __restrict__ s, const float acc[8][4], int rg, int oc0) {
#pragma unroll
    for (int j = 0; j < 8; ++j) {
        float4 t; t.x = acc[j][0]; t.y = acc[j][1]; t.z = acc[j][2]; t.w = acc[j][3];
        *(float4*)(s + (rg * 8 + j) * C + oc0) = t;
    }
}

// ============================================================================
// pack 4 weight matrices into MFMA B-fragment order (bf16), f = ks*8+nt
// lane L holds k = ks*32 + (L>>4)*8 + j,  n = nt*16 + (L&15)
// ============================================================================
extern "C" __global__ void pack_w(const float* __restrict__ w0, const float* __restrict__ w1,
                                  const float* __restrict__ w2, const float* __restrict__ w3,
                                  ushortT* __restrict__ out)
{
    const int t = blockIdx.x * 256 + threadIdx.x;      // 65536 threads
    const int j = t & 7, lane = (t >> 3) & 63, f = (t >> 9) & 31, s = t >> 14;
    const float* W = (s == 0) ? w0 : (s == 1) ? w1 : (s == 2) ? w2 : w3;
    const int nt = f & 7, ks = f >> 3;
    const int n = nt * 16 + (lane & 15);
    const int k = ks * 32 + (lane >> 4) * 8 + j;
    out[t] = f2bf(W[k * C + n]);
}

extern "C" __global__ void cvt_bf(const float* __restrict__ in, ushortT* __restrict__ out, int n)
{
    const int t = blockIdx.x * 256 + threadIdx.x;
    if (t < n) out[t] = f2bf(in[t]);
}

// ============================================================================
// kernel 1: h = relu(x@W_in+b_in); q_bf; k_bf; v_bf
// ============================================================================
extern "C" __global__ void __launch_bounds__(THREADS)
node_qkv(const float* __restrict__ x,
         const float* __restrict__ W_in, const float* __restrict__ b_in,
         const float* __restrict__ W_lin, const float* __restrict__ W_src, const float* __restrict__ W_dst,
         ushortT* __restrict__ q_bf, ushortT* __restrict__ k_bf, ushortT* __restrict__ v_bf, int N)
{
    __shared__ __align__(16) float s_in[TILE * C];
    const int tx = threadIdx.x;
    const int rg = tx >> 5;
    const int oc0 = (tx & 31) << 2;
    const int row0 = blockIdx.x * TILE;

#pragma unroll
    for (int j = 0; j < 8; ++j) {
        const int r = rg * 8 + j, n = row0 + r;
        float4 xv; xv.x = xv.y = xv.z = xv.w = 0.f;
        if (n < N) xv = *(const float4*)(x + n * C + oc0);
        *(float4*)(s_in + r * C + oc0) = xv;
    }

    float acc[8][4];
    zero_acc(acc);
    tile_gemm(s_in, W_in, acc, rg, oc0);
    bias_relu(acc, b_in, oc0);
    store_tile(s_in, acc, rg, oc0);          // s_in = h

    ushortT* outs[3];
    const float* Ws[3];
    outs[0] = q_bf; outs[1] = k_bf; outs[2] = v_bf;
    Ws[0] = W_dst;  Ws[1] = W_src;  Ws[2] = W_lin;
#pragma unroll 1
    for (int m = 0; m < 3; ++m) {
        zero_acc(acc);
        tile_gemm(s_in, Ws[m], acc, rg, oc0);
#pragma unroll
        for (int j = 0; j < 8; ++j) {
            const int n = row0 + rg * 8 + j;
            if (n < N) {
                ushort4 t; t.x = f2bf(acc[j][0]); t.y = f2bf(acc[j][1]);
                t.z = f2bf(acc[j][2]); t.w = f2bf(acc[j][3]);
                *(ushort4*)(outs[m] + (size_t)n * C + oc0) = t;
            }
        }
    }
}

// ============================================================================
// kernel 2 (MFMA): line-coherent gathers. Lane mapping: row = lane>>2,
// li = lane&3; per instruction the 4 lanes of a row-group read ONE contiguous
// 64B line (node*256B + i*64B + li*16B) -> 16 lines/inst instead of 64.
// 16 edges/wave-tile, GTILES-deep rolled loop, per-wave LDS slabs, NO barriers.
// A-frag:  A[m=lane&15][k=quad*8+j]     C-frag: C[m=quad*4+r][n=lane&15]
// ============================================================================
__device__ __forceinline__ void gather4(const ushortT* __restrict__ base, int node, int li,
                                        ushort8 dst[4])
{
    const ushort8* p = (const ushort8*)(base + (size_t)node * C) + li;
    dst[0] = p[0]; dst[1] = p[4]; dst[2] = p[8]; dst[3] = p[12];   // chunk i at ushort8 index i*4+li
}

__device__ __forceinline__ void wave_gemm(const ushortT (*A)[LDSW],
                                          const ushortT* __restrict__ Bp,
                                          int quad, int m16, int lane,
                                          floatx4 acc[8])
{
#pragma unroll
    for (int nt = 0; nt < 8; ++nt) { acc[nt][0]=0.f; acc[nt][1]=0.f; acc[nt][2]=0.f; acc[nt][3]=0.f; }
#pragma unroll 1
    for (int ks = 0; ks < 4; ++ks) {
        const short8 af = *(const short8*)&A[m16][ks * 32 + quad * 8];
        const ushortT* bpk = Bp + (size_t)ks * 4096 + (size_t)lane * 8;
#pragma unroll
        for (int nt = 0; nt < 8; ++nt) {
            const short8 bf = *(const short8*)(bpk + nt * 512);
            acc[nt] = __builtin_amdgcn_mfma_f32_16x16x32_bf16(af, bf, acc[nt], 0, 0, 0);
        }
    }
}

__device__ __forceinline__ void cstore_relu_r(ushortT (*A)[LDSW], floatx4 acc[8],
                                              const float bias[8], int quad, int m16)
{
#pragma unroll
    for (int nt = 0; nt < 8; ++nt) {
        const float b = bias[nt];
#pragma unroll
        for (int r = 0; r < 4; r += 2) {
            const unsigned p = pk2(fmaxf(acc[nt][r] + b, 0.f), fmaxf(acc[nt][r + 1] + b, 0.f));
            A[quad * 4 + r][nt * 16 + m16]     = (ushortT)(p & 0xffffu);
            A[quad * 4 + r + 1][nt * 16 + m16] = (ushortT)(p >> 16);
        }
    }
}

extern "C" __global__ void __launch_bounds__(THREADS)
edge_mfma(const ushortT* __restrict__ pos_bf, const int* __restrict__ ei,
          const ushortT* __restrict__ q_bf, const ushortT* __restrict__ k_bf,
          const ushortT* __restrict__ v_bf, const ushortT* __restrict__ Bpack,
          const float* __restrict__ pb1, const float* __restrict__ pb2,
          const float* __restrict__ ab1, const float* __restrict__ ab2,
          float* __restrict__ z, float* __restrict__ aggU, int E)
{
    __shared__ ushortT Aslab[4][EPW][LDSW];   // 17.4 KB
    __shared__ ushortT Vslab[4][EPW][LDSW];   // 17.4 KB
    const int tid = threadIdx.x;
    const int wv = tid >> 6, lane = tid & 63;
    const int quad = lane >> 4, m16 = lane & 15;
    const int row = lane >> 2, li = lane & 3;      // line-coherent staging mapping
    ushortT (*A)[LDSW] = Aslab[wv];
    ushortT (*V)[LDSW] = Vslab[wv];

    // tile-invariant: biases in registers
    float pb1v[8], pb2v[8], ab1v[8], ab2v[8];
#pragma unroll
    for (int nt = 0; nt < 8; ++nt) {
        pb1v[nt] = pb1[nt * 16 + m16]; pb2v[nt] = pb2[nt * 16 + m16];
        ab1v[nt] = ab1[nt * 16 + m16]; ab2v[nt] = ab2[nt * 16 + m16];
    }

    const ushortT* B0 = Bpack;
    const ushortT* B1 = Bpack + 16384;
    const ushortT* B2 = Bpack + 32768;
    const ushortT* B3 = Bpack + 49152;

    const int wave_base = (blockIdx.x * 4 + wv) * (GTILES * EPW);

#pragma unroll 1
    for (int t = 0; t < GTILES; ++t) {
        const int e_base = wave_base + t * EPW;
        const int eidx = min(e_base + row, E - 1);
        const int es = ei[eidx], ed = ei[E + eidx];
        int sdr[4];
#pragma unroll
        for (int r = 0; r < 4; ++r)
            sdr[r] = ei[E + min(e_base + quad * 4 + r, E - 1)];

        ushort8 Pd[4], Ps[4], Qv[4], Kv[4], Vv[4];
        gather4(pos_bf, ed, li, Pd); gather4(pos_bf, es, li, Ps);
        gather4(q_bf,  ed, li, Qv); gather4(k_bf,  es, li, Kv);
        gather4(v_bf,  es, li, Vv);

        // ---- A0 = bf16(pos[dst] - pos[src]); stage v into Vslab ----
        // lane's chunk i lives at ushort offset i*32 + li*8 within the row
#pragma unroll
        for (int i = 0; i < 4; ++i) {
            const uintx4 pd = *(const uintx4*)&Pd[i];
            const uintx4 ps = *(const uintx4*)&Ps[i];
            uintx4 o;
#pragma unroll
            for (int w = 0; w < 4; ++w) {
                const float2 a = upk2(pd[w]), b = upk2(ps[w]);
                o[w] = pk2(a.x - b.x, a.y - b.y);
            }
            *(uintx4*)&A[row][i * 32 + li * 8] = o;
            *(ushort8*)&V[row][i * 32 + li * 8] = Vv[i];
        }

        floatx4 acc[8];

        // ---- pos_nn layer 1 ----
        wave_gemm(A, B0, quad, m16, lane, acc);
        cstore_relu_r(A, acc, pb1v, quad, m16);

        // ---- pos_nn layer 2 -> delta (packed regs + slab) ----
        wave_gemm(A, B1, quad, m16, lane, acc);
        unsigned dlp[8][2];
#pragma unroll
        for (int nt = 0; nt < 8; ++nt) {
            const float b = pb2v[nt];
            const unsigned p0 = pk2(fmaxf(acc[nt][0] + b, 0.f), fmaxf(acc[nt][1] + b, 0.f));
            const unsigned p1 = pk2(fmaxf(acc[nt][2] + b, 0.f), fmaxf(acc[nt][3] + b, 0.f));
            dlp[nt][0] = p0; dlp[nt][1] = p1;
            A[quad * 4 + 0][nt * 16 + m16] = (ushortT)(p0 & 0xffffu);
            A[quad * 4 + 1][nt * 16 + m16] = (ushortT)(p0 >> 16);
            A[quad * 4 + 2][nt * 16 + m16] = (ushortT)(p1 & 0xffffu);
            A[quad * 4 + 3][nt * 16 + m16] = (ushortT)(p1 >> 16);
        }

        // ---- A2 = bf16( q[dst] - k[src] + delta ) ----
#pragma unroll
        for (int i = 0; i < 4; ++i) {
            const uintx4 dv = *(const uintx4*)&A[row][i * 32 + li * 8];
            const uintx4 qv = *(const uintx4*)&Qv[i];
            const uintx4 kv = *(const uintx4*)&Kv[i];
            uintx4 o;
#pragma unroll
            for (int w = 0; w < 4; ++w) {
                const float2 qq = upk2(qv[w]), kk = upk2(kv[w]), dd = upk2(dv[w]);
                o[w] = pk2(qq.x - kk.x + dd.x, qq.y - kk.y + dd.y);
            }
            *(uintx4*)&A[row][i * 32 + li * 8] = o;
        }

        // ---- attn_nn layer 1 ----
        wave_gemm(A, B2, quad, m16, lane, acc);
        cstore_relu_r(A, acc, ab1v, quad, m16);

        // ---- attn_nn layer 2 -> ea = exp(relu(alpha+b)) ----
        wave_gemm(A, B3, quad, m16, lane, acc);
#pragma unroll
        for (int nt = 0; nt < 8; ++nt) {
            const float b = ab2v[nt];
#pragma unroll
            for (int r = 0; r < 4; ++r)
                acc[nt][r] = __expf(fmaxf(acc[nt][r] + b, 0.f));  // alpha>=0, O(1): no max-shift
        }

        // ---- zero ea for out-of-range edges ----
        if (e_base + EPW > E) {
#pragma unroll
            for (int r = 0; r < 4; ++r)
                if (e_base + quad * 4 + r >= E) {
#pragma unroll
                    for (int nt = 0; nt < 8; ++nt) acc[nt][r] = 0.f;
                }
        }

        // ---- epilogue: z += ea; aggU += ea*(v+delta) ----
#pragma unroll
        for (int r = 0; r < 4; ++r) {
            float* zp = z    + (size_t)sdr[r] * C + m16;
            float* gp = aggU + (size_t)sdr[r] * C + m16;
#pragma unroll
            for (int nt = 0; nt < 8; ++nt) {
                const float ea  = acc[nt][r];
                const float2 dpair = upk2(dlp[nt][r >> 1]);
                const float dlv = (r & 1) ? dpair.y : dpair.x;
                const float vv  = bf2f(V[quad * 4 + r][nt * 16 + m16]);
                atomic_add_f32(zp + nt * 16, ea);
                atomic_add_f32(gp + nt * 16, ea * (vv + dlv));
            }
        }
    }
}

// ============================================================================
// kernel 3: out = relu( (aggU / (z+1e-16)) @ W_out + b_out )
// ============================================================================
extern "C" __global__ void __launch_bounds__(THREADS)
out_kernel(const float* __restrict__ aggU, const float* __restrict__ z,
           const float* __restrict__ W_out, const float* __restrict__ b_out,
           float* __restrict__ out, int N)
{
    __shared__ __align__(16) float s_in[TILE * C];
    const int tx = threadIdx.x;
    const int rg = tx >> 5;
    const int oc0 = (tx & 31) << 2;
    const int row0 = blockIdx.x * TILE;

#pragma unroll
    for (int j = 0; j < 8; ++j) {
        const int r = rg * 8 + j, n = row0 + r;
        float4 a; a.x = a.y = a.z = a.w = 0.f;
        if (n < N) {
            const float4 g  = *(const float4*)(aggU + (size_t)n * C + oc0);
            const float4 zz = *(const float4*)(z    + (size_t)n * C + oc0);
            a.x = g.x / (zz.x + 1e-16f);
            a.y = g.y / (zz.y + 1e-16f);
            a.z = g.z / (zz.z + 1e-16f);
            a.w = g.w / (zz.w + 1e-16f);
        }
        *(float4*)(s_in + r * C + oc0) = a;
    }

    float acc[8][4];
    zero_acc(acc);
    tile_gemm(s_in, W_out, acc, rg, oc0);
    bias_relu(acc, b_out, oc0);
#pragma unroll
    for (int j = 0; j < 8; ++j) {
        const int n = row0 + rg * 8 + j;
        if (n < N) { float4 t; t.x=acc[j][0]; t.y=acc[j][1]; t.z=acc[j][2]; t.w=acc[j][3];
                     *(float4*)(out + (size_t)n * C + oc0) = t; }
    }
}

// ---------------------------------------------------------------------------
extern "C" void kernel_launch(void* const* d_in, const int* in_sizes, int n_in,
                              void* d_out, int out_size, void* d_ws, size_t ws_size,
                              hipStream_t stream)
{
    const float* x     = (const float*)d_in[0];
    const float* pos   = (const float*)d_in[1];
    const int*   ei    = (const int*)  d_in[2];
    const float* W_in  = (const float*)d_in[3];
    const float* b_in  = (const float*)d_in[4];
    const float* W_lin = (const float*)d_in[5];
    const float* W_src = (const float*)d_in[6];
    const float* W_dst = (const float*)d_in[7];
    const float* pw1   = (const float*)d_in[8];
    const float* pb1   = (const float*)d_in[9];
    const float* pw2   = (const float*)d_in[10];
    const float* pb2   = (const float*)d_in[11];
    const float* aw1   = (const float*)d_in[12];
    const float* ab1   = (const float*)d_in[13];
    const float* aw2   = (const float*)d_in[14];
    const float* ab2   = (const float*)d_in[15];
    const float* W_out = (const float*)d_in[16];
    const float* b_out = (const float*)d_in[17];

    const int N = in_sizes[0] / C;
    const int E = in_sizes[2] / 2;
    const size_t NC = (size_t)N * C;

    float*   z      = (float*)d_ws;                          // [N,C] fp32
    float*   aggU   = z    + NC;                             // [N,C] fp32
    ushortT* q_bf   = (ushortT*)(aggU + NC);                 // [N,C] bf16
    ushortT* k_bf   = q_bf + NC;                             // [N,C] bf16
    ushortT* v_bf   = k_bf + NC;                             // [N,C] bf16
    ushortT* pos_bf = v_bf + NC;                             // [N,C] bf16
    ushortT* Bpack  = pos_bf + NC;                           // 65536 bf16 = 128 KB

    hipMemsetAsync(z, 0, 2 * NC * sizeof(float), stream);

    pack_w<<<256, 256, 0, stream>>>(pw1, pw2, aw1, aw2, Bpack);
    cvt_bf<<<((int)NC + 255) / 256, 256, 0, stream>>>(pos, pos_bf, (int)NC);

    const int nb = (N + TILE - 1) / TILE;
    const int edges_per_block = 4 * GTILES * EPW;            // 512
    const int eb = (E + edges_per_block - 1) / edges_per_block;

    node_qkv<<<nb, THREADS, 0, stream>>>(x, W_in, b_in, W_lin, W_src, W_dst, q_bf, k_bf, v_bf, N);
    edge_mfma<<<eb, THREADS, 0, stream>>>(pos_bf, ei, q_bf, k_bf, v_bf, Bpack,
                                          pb1, pb2, ab1, ab2, z, aggU, E);
    out_kernel<<<nb, THREADS, 0, stream>>>(aggU, z, W_out, b_out, (float*)d_out, N);
}